// Round 7
// baseline (477.913 us; speedup 1.0000x reference)
//
#include <hip/hip_runtime.h>

#define NN 100000
#define MM 25000
#define EE 600000
#define TT (MM + NN)

#define CVT_BLOCKS 12500              // NN*128/4/256 exact
#define NB 782                        // 391 he buckets (h>>6) + 391 nd buckets (n>>8)
#define CAP 2048                      // bucket capacity (expected 1536, sigma ~39)
#define TILE_E 4096
#define GA ((EE + TILE_E - 1) / TILE_E)   // 147

#define GB_HE 1563                    // he tiles: ceil(25000/16)
#define NT_ND 6250                    // nd tiles: 100000/16
#define GB_ND 2048

typedef __attribute__((ext_vector_type(8))) short short8;
typedef __attribute__((ext_vector_type(4))) float floatx4;

__device__ __forceinline__ float bl(unsigned int u){ return __uint_as_float(u << 16); }
__device__ __forceinline__ float bh(unsigned int u){ return __uint_as_float(u & 0xffff0000u); }
__device__ __forceinline__ unsigned int packbf2(float a, float b){
    unsigned int ua = __float_as_uint(a), ub = __float_as_uint(b);
    ua = (ua + 0x7fffu + ((ua >> 16) & 1u)) >> 16;
    ub = (ub + 0x7fffu + ((ub >> 16) & 1u)) & 0xffff0000u;
    return ua | ub;
}
__device__ __forceinline__ unsigned short f2bf(float f){
    unsigned int u = __float_as_uint(f);
    return (unsigned short)((u + 0x7fffu + ((u >> 16) & 1u)) >> 16);
}

// ---------------- preamble: x->bf16 | weight transpose | bucket-cursor init ----------------
__global__ void k_setup(const float* __restrict__ x, unsigned int* __restrict__ xb,
                        const float* __restrict__ W1, const float* __restrict__ W2,
                        const float* __restrict__ W3, unsigned short* __restrict__ WT,
                        int* __restrict__ gcur) {
    int b = blockIdx.x;
    if (b < CVT_BLOCKS) {
        int t = b * 256 + threadIdx.x;
        float4 v = ((const float4*)x)[t];
        uint2 o; o.x = packbf2(v.x, v.y); o.y = packbf2(v.z, v.w);
        ((uint2*)xb)[t] = o;
    } else if (b < CVT_BLOCKS + 3) {
        int l = b - CVT_BLOCKS;
        const float* W = l == 0 ? W1 : (l == 1 ? W2 : W3);
        unsigned short* T = WT + l * 16384;
        for (int i = threadIdx.x; i < 16384; i += 256) {
            int k = i >> 7, c = i & 127;
            T[c * 128 + k] = f2bf(W[k * 128 + c]);
        }
    } else {
        for (int i = threadIdx.x; i < NB; i += 256) gcur[i] = i * CAP;
    }
}

// ---------------- CSR build pass A: LDS hist -> reserve -> scatter into padded buckets --------
// he item: ((h&63)<<17)|n  in buckets [0,391); nd item: ((n&255)<<15)|h in [391,782).
__global__ __launch_bounds__(256) void k_binA(const int* __restrict__ nidx, const int* __restrict__ hidx,
                                              int* __restrict__ gcur, unsigned int* __restrict__ items) {
    __shared__ int h[NB];
    __shared__ int cur[NB];
    int t = threadIdx.x;
    for (int i = t; i < NB; i += 256) h[i] = 0;
    __syncthreads();
    int base = blockIdx.x * TILE_E;
    #pragma unroll
    for (int k = 0; k < 16; k++) {
        int e = base + k * 256 + t;
        if (e < EE) {
            atomicAdd(&h[hidx[e] >> 6], 1);
            atomicAdd(&h[391 + (nidx[e] >> 8)], 1);
        }
    }
    __syncthreads();
    for (int i = t; i < NB; i += 256) {
        int c = h[i];
        cur[i] = c ? atomicAdd(&gcur[i], c) : 0;
    }
    __syncthreads();
    #pragma unroll
    for (int k = 0; k < 16; k++) {
        int e = base + k * 256 + t;
        if (e < EE) {
            int hh = hidx[e], nn = nidx[e];
            int p1 = atomicAdd(&cur[hh >> 6], 1);
            items[p1] = ((unsigned)(hh & 63) << 17) | (unsigned)nn;
            int p2 = atomicAdd(&cur[391 + (nn >> 8)], 1);
            items[p2] = ((unsigned)(nn & 255) << 15) | (unsigned)hh;
        }
    }
}

// ---------------- pass B: per-bucket group-by-key; emit ptr2{beg,deg}, inv, grouped adj --------
__global__ __launch_bounds__(256) void k_passB(unsigned int* __restrict__ items,  // adj, in place
                                               const int* __restrict__ gcur,
                                               int2* __restrict__ ptr2, float* __restrict__ inv) {
    __shared__ unsigned int led[CAP];
    __shared__ unsigned int grp[CAP];
    __shared__ int bins[256], cur[256], tmp[256];
    int b = blockIdx.x, t = threadIdx.x;
    int base = b * CAP, cnt = gcur[b] - base;
    bool he = b < 391;
    int nbins = he ? 64 : 256;
    int keybase = he ? b * 64 : MM + (b - 391) * 256;
    int shift = he ? 17 : 15;
    unsigned int mask = he ? 0x1FFFFu : 0x7FFFu;
    int keylim = he ? MM : TT;

    for (int i = t; i < cnt; i += 256) led[i] = items[base + i];
    bins[t] = 0;
    __syncthreads();
    for (int i = t; i < cnt; i += 256) atomicAdd(&bins[led[i] >> shift], 1);
    __syncthreads();
    int v = (t < nbins) ? bins[t] : 0;
    tmp[t] = v;
    __syncthreads();
    for (int o = 1; o < 256; o <<= 1) {
        int u = (t >= o) ? tmp[t - o] : 0;
        __syncthreads();
        tmp[t] += u;
        __syncthreads();
    }
    int excl = tmp[t] - v;
    if (t < nbins) {
        int g = keybase + t;
        if (g < keylim) {
            ptr2[g] = make_int2(base + excl, v);
            inv[g] = v ? 1.f / (float)v : 0.f;
        }
        cur[t] = excl;
    }
    __syncthreads();
    for (int i = t; i < cnt; i += 256) {
        unsigned int it = led[i];
        int p = atomicAdd(&cur[it >> shift], 1);
        grp[p] = it & mask;
    }
    __syncthreads();
    for (int i = t; i < cnt; i += 256) items[base + i] = grp[i];
}

// ---------------- he-gather, 4 feature phases (32 feat = 64B/row/phase) ----------------
// All blocks co-resident; phase-major loop keeps the whole device on one 6.4MB slice at a time.
__global__ __launch_bounds__(256) void k_gather_heq(const unsigned int* __restrict__ X,
        const int2* __restrict__ ptr2, const unsigned int* __restrict__ adj,
        const float* __restrict__ b_inv, unsigned int* __restrict__ sbuf) {
    int t = threadIdx.x;
    int qidx = t >> 4, ql = t & 15;
    int r = blockIdx.x * 16 + qidx;
    if (r >= MM) return;
    int2 pe = ptr2[r];
    float sc = b_inv[r];
    int end = pe.x + pe.y;
    #pragma unroll
    for (int p = 0; p < 4; ++p) {
        float a0 = 0.f, a1 = 0.f;
        for (int j = pe.x; j < end; j += 8) {
            int c = end - j;
            int n[8];
            #pragma unroll
            for (int i = 0; i < 8; i++) n[i] = (i < c) ? (int)adj[j + i] : 0;
            unsigned int v[8];
            #pragma unroll
            for (int i = 0; i < 8; i++) {
                v[i] = 0u;
                if (i < c) v[i] = X[(unsigned)n[i] * 64u + p * 16 + ql];
            }
            #pragma unroll
            for (int i = 0; i < 8; i++) { a0 += bl(v[i]); a1 += bh(v[i]); }
        }
        sbuf[(unsigned)r * 64u + p * 16 + ql] = packbf2(a0 * sc, a1 * sc);
    }
}

// ---------------- nd-gather, 2 feature phases (64 feat = 128B/row/phase), fused epilogue ------
template<bool F32OUT>
__global__ __launch_bounds__(256) void k_gather_ndh(const unsigned int* __restrict__ X,
        const int2* __restrict__ ptr2, const unsigned int* __restrict__ adj,
        const float* __restrict__ d_inv, const float* __restrict__ bias, void* __restrict__ out) {
    int t = threadIdx.x;
    int qidx = t >> 4, ql = t & 15;
    const uint2* X2 = (const uint2*)X;
    #pragma unroll
    for (int p = 0; p < 2; ++p) {
        for (int tile = blockIdx.x; tile < NT_ND; tile += GB_ND) {
            int r = tile * 16 + qidx;
            if (r >= NN) continue;
            int2 pe = ptr2[r];
            int end = pe.x + pe.y;
            float a0 = 0.f, a1 = 0.f, a2 = 0.f, a3 = 0.f;
            for (int j = pe.x; j < end; j += 8) {
                int c = end - j;
                int n[8];
                #pragma unroll
                for (int i = 0; i < 8; i++) n[i] = (i < c) ? (int)adj[j + i] : 0;
                uint2 v[8];
                #pragma unroll
                for (int i = 0; i < 8; i++) {
                    v[i] = make_uint2(0u, 0u);
                    if (i < c) v[i] = X2[(unsigned)n[i] * 32u + p * 16 + ql];
                }
                #pragma unroll
                for (int i = 0; i < 8; i++) {
                    a0 += bl(v[i].x); a1 += bh(v[i].x);
                    a2 += bl(v[i].y); a3 += bh(v[i].y);
                }
            }
            float sc = d_inv[r];
            float4 bb = ((const float4*)bias)[p * 16 + ql];
            float f0 = a0 * sc + bb.x, f1 = a1 * sc + bb.y;
            float f2 = a2 * sc + bb.z, f3 = a3 * sc + bb.w;
            f0 = f0 > 0.f ? f0 : __expf(f0) - 1.f;
            f1 = f1 > 0.f ? f1 : __expf(f1) - 1.f;
            f2 = f2 > 0.f ? f2 : __expf(f2) - 1.f;
            f3 = f3 > 0.f ? f3 : __expf(f3) - 1.f;
            if (F32OUT) {
                ((float4*)out)[(unsigned)r * 32u + p * 16 + ql] = make_float4(f0, f1, f2, f3);
            } else {
                ((uint2*)out)[(unsigned)r * 32u + p * 16 + ql] = make_uint2(packbf2(f0, f1), packbf2(f2, f3));
            }
        }
    }
}

// ---------------- GEMM  m[MM,128] = s[MM,128] @ W  (WT is W^T, bf16) ----------------
__global__ __launch_bounds__(256) void k_gemm(const unsigned short* __restrict__ A,
                                              const unsigned short* __restrict__ WT,
                                              unsigned short* __restrict__ C) {
    int lane = threadIdx.x & 63;
    int wv = threadIdx.x >> 6;
    int r0 = blockIdx.x * 64 + wv * 16;
    int mm = lane & 15;
    int quad = lane >> 4;
    floatx4 acc[8];
    #pragma unroll
    for (int c = 0; c < 8; c++) acc[c] = (floatx4){0.f, 0.f, 0.f, 0.f};
    int arow = r0 + mm; if (arow >= MM) arow = MM - 1;
    #pragma unroll
    for (int q = 0; q < 4; q++) {
        short8 af = *reinterpret_cast<const short8*>(A + arow * 128 + q * 32 + quad * 8);
        #pragma unroll
        for (int c = 0; c < 8; c++) {
            short8 bf = *reinterpret_cast<const short8*>(WT + (c * 16 + mm) * 128 + q * 32 + quad * 8);
            acc[c] = __builtin_amdgcn_mfma_f32_16x16x32_bf16(af, bf, acc[c], 0, 0, 0);
        }
    }
    #pragma unroll
    for (int c = 0; c < 8; c++) {
        #pragma unroll
        for (int r = 0; r < 4; r++) {
            int row = r0 + quad * 4 + r;
            if (row < MM) C[row * 128 + c * 16 + mm] = f2bf(acc[c][r]);
        }
    }
}

extern "C" void kernel_launch(void* const* d_in, const int* in_sizes, int n_in,
                              void* d_out, int out_size, void* d_ws, size_t ws_size,
                              hipStream_t stream) {
    const float* x  = (const float*)d_in[0];
    const float* W1 = (const float*)d_in[1];
    const float* b1 = (const float*)d_in[2];
    const float* W2 = (const float*)d_in[3];
    const float* b2 = (const float*)d_in[4];
    const float* W3 = (const float*)d_in[5];
    const float* b3 = (const float*)d_in[6];
    const int* nidx = (const int*)d_in[7];
    const int* hidx = (const int*)d_in[8];

    char* ws = (char*)d_ws;
    size_t o = 0;
    auto alloc = [&](size_t b) -> char* { char* p = ws + o; o = (o + b + 255) & ~(size_t)255; return p; };
    int2*  ptr2  = (int2*)alloc((size_t)TT * 8);
    float* invq  = (float*)alloc(TT * 4);                  // [0,MM): b_inv ; [MM,TT): d_inv
    int*   gcur  = (int*)alloc(NB * 4);
    unsigned int* items = (unsigned int*)alloc((size_t)NB * CAP * 4);  // padded buckets -> grouped adj
    unsigned short* WT   = (unsigned short*)alloc(3 * 128 * 128 * 2);
    unsigned short* sbuf = (unsigned short*)alloc((size_t)MM * 128 * 2);
    unsigned short* mbuf = (unsigned short*)alloc((size_t)MM * 128 * 2);

    // d_out hosts: xb/bufA (first half), bufB (second half), final f32 (all)
    unsigned int* xb   = (unsigned int*)d_out;
    unsigned int* bufA = (unsigned int*)d_out;
    unsigned int* bufB = (unsigned int*)d_out + (size_t)NN * 64;

    k_setup<<<CVT_BLOCKS + 4, 256, 0, stream>>>(x, xb, W1, W2, W3, WT, gcur);
    k_binA<<<GA, 256, 0, stream>>>(nidx, hidx, gcur, items);
    k_passB<<<NB, 256, 0, stream>>>(items, gcur, ptr2, invq);

    const float* b_inv = invq;
    const float* d_inv = invq + MM;
    const int2* nptr2 = ptr2 + MM;
    const unsigned int* adj = items;
    const int grid_gm = (MM + 63) / 64;              // 391

    // Layer 0
    k_gather_heq<<<GB_HE, 256, 0, stream>>>(xb, ptr2, adj, b_inv, (unsigned int*)sbuf);
    k_gemm<<<grid_gm, 256, 0, stream>>>(sbuf, WT, mbuf);
    k_gather_ndh<false><<<GB_ND, 256, 0, stream>>>((const unsigned int*)mbuf, nptr2, adj, d_inv, b1, (void*)bufA);
    // Layer 1
    k_gather_heq<<<GB_HE, 256, 0, stream>>>(bufA, ptr2, adj, b_inv, (unsigned int*)sbuf);
    k_gemm<<<grid_gm, 256, 0, stream>>>(sbuf, WT + 16384, mbuf);
    k_gather_ndh<false><<<GB_ND, 256, 0, stream>>>((const unsigned int*)mbuf, nptr2, adj, d_inv, b2, (void*)bufB);
    // Layer 2
    k_gather_heq<<<GB_HE, 256, 0, stream>>>(bufB, ptr2, adj, b_inv, (unsigned int*)sbuf);
    k_gemm<<<grid_gm, 256, 0, stream>>>(sbuf, WT + 32768, mbuf);
    k_gather_ndh<true ><<<GB_ND, 256, 0, stream>>>((const unsigned int*)mbuf, nptr2, adj, d_inv, b3, d_out);
}